// Round 3
// baseline (1455.770 us; speedup 1.0000x reference)
//
#include <hip/hip_runtime.h>
#include <stdint.h>

#define E_  8
#define D_  1024
#define H_  4096
#define T_  32768
#define TPE 4096   // tokens per expert (uniform splits)

typedef __bf16 bf16x8 __attribute__((ext_vector_type(8)));
typedef float  f32x4  __attribute__((ext_vector_type(4)));
typedef unsigned short u16x4 __attribute__((ext_vector_type(4)));
typedef unsigned short u16x8 __attribute__((ext_vector_type(8)));

__device__ __forceinline__ unsigned short f2bf(float f) {
  union { float f; uint32_t u; } v; v.f = f;
  uint32_t u = v.u;
  return (unsigned short)((u + 0x7FFFu + ((u >> 16) & 1u)) >> 16);  // RNE
}

// async global->LDS, 16B per lane; LDS dest = wave-uniform base + lane*16
__device__ __forceinline__ void gld16(const unsigned short* g, unsigned short* l) {
  __builtin_amdgcn_global_load_lds(
      (const __attribute__((address_space(1))) unsigned int*)g,
      (__attribute__((address_space(3))) unsigned int*)l, 16, 0, 0);
}

__device__ __forceinline__ f32x4 mfma_bf16(bf16x8 a, bf16x8 b, f32x4 c) {
  return __builtin_amdgcn_mfma_f32_16x16x32_bf16(a, b, c, 0, 0, 0);
}

// ---------------- fp32 -> bf16 straight convert (x) ----------------
__global__ void cvt_bf16(const float* __restrict__ in, unsigned short* __restrict__ out) {
  size_t i = ((size_t)blockIdx.x * 256 + threadIdx.x) * 8;
  float4 a = *(const float4*)(in + i);
  float4 b = *(const float4*)(in + i + 4);
  u16x8 o;
  o[0] = f2bf(a.x); o[1] = f2bf(a.y); o[2] = f2bf(a.z); o[3] = f2bf(a.w);
  o[4] = f2bf(b.x); o[5] = f2bf(b.y); o[6] = f2bf(b.z); o[7] = f2bf(b.w);
  *(u16x8*)(out + i) = o;
}

// ------------- fp32 [R][C] -> bf16 [C][R] per expert (plain, for w2) -------------
__global__ void transpose_bf16(const float* __restrict__ in, unsigned short* __restrict__ out,
                               int R, int C) {
  __shared__ unsigned short t[64][68];
  size_t eo = (size_t)blockIdx.z * R * C;
  const float* ine = in + eo;
  unsigned short* oute = out + eo;
  int r0 = blockIdx.y * 64, c0 = blockIdx.x * 64;
  int rl = threadIdx.x >> 4;
  int cl = (threadIdx.x & 15) * 4;
#pragma unroll
  for (int i = 0; i < 4; ++i) {
    int r = i * 16 + rl;
    float4 v = *(const float4*)(ine + (size_t)(r0 + r) * C + c0 + cl);
    t[cl + 0][r] = f2bf(v.x);
    t[cl + 1][r] = f2bf(v.y);
    t[cl + 2][r] = f2bf(v.z);
    t[cl + 3][r] = f2bf(v.w);
  }
  __syncthreads();
#pragma unroll
  for (int i = 0; i < 4; ++i) {
    int c = i * 16 + rl;
    *(u16x4*)(oute + (size_t)(c0 + c) * R + r0 + cl) = *(const u16x4*)&t[c][cl];
  }
}

// ---- fp32 [R][C] -> bf16 interleaved B' [2C][R]: source col cc -> out row
// 32*(cc>>4) + (cc&15) + off   (off=0: w1/gate 16-group, off=16: w3/up 16-group)
__global__ void transpose_ilv_bf16(const float* __restrict__ in, unsigned short* __restrict__ out,
                                   int R, int C, int off) {
  __shared__ unsigned short t[64][68];
  const float* ine = in + (size_t)blockIdx.z * R * C;
  unsigned short* oute = out + (size_t)blockIdx.z * 2 * (size_t)R * C;
  int r0 = blockIdx.y * 64, c0 = blockIdx.x * 64;
  int rl = threadIdx.x >> 4;
  int cl = (threadIdx.x & 15) * 4;
#pragma unroll
  for (int i = 0; i < 4; ++i) {
    int r = i * 16 + rl;
    float4 v = *(const float4*)(ine + (size_t)(r0 + r) * C + c0 + cl);
    t[cl + 0][r] = f2bf(v.x);
    t[cl + 1][r] = f2bf(v.y);
    t[cl + 2][r] = f2bf(v.z);
    t[cl + 3][r] = f2bf(v.w);
  }
  __syncthreads();
#pragma unroll
  for (int i = 0; i < 4; ++i) {
    int c = i * 16 + rl;
    int rr = c0 + c;
    int orow = 32 * (rr >> 4) + (rr & 15) + off;
    *(u16x4*)(oute + (size_t)orow * R + r0 + cl) = *(const u16x4*)&t[c][cl];
  }
}

// =====================================================================
// 256x256 8-wave pipelined GEMM core. BK=64, double-buffered LDS (128KB),
// 4-phase K-step, counted vmcnt, raw s_barrier, setprio around MFMA.
// A [M][K], B [N][K], both k-contiguous (B is B^T).
// LDS layout: chunk = 16 rows x 32 k (1KB), fragment-ordered (lane l = kq*16+r
// holds row r, k-quad kq) -> ds_read_b128 is a contiguous 1KB/wave, conflict-free.
// A tile = 32 chunks (chunk idx = rowgroup*2 + kchunk); wave w stages chunks w+8q.
//
// ROUND-3 SCHEDULE (deepened prefetch, 2 full tiles ahead):
//   All staging for tile u+2 happens at tile u's p3 (B, 4 loads) and p4
//   (A, 4 loads). Region safety: ALL B reads of tile u (chunks 0-31, across
//   waves) complete by p2's closing barrier -> p3 may overwrite any cB chunk;
//   ALL A reads complete by p3's closing barrier -> p4 may overwrite any cA
//   chunk. Every load is issued >=5 phases (~1250 cyc) before first use,
//   covering HBM-class latency (round-2's half1 loads had only ~2 phases ->
//   vmcnt stall every K-tile, MfmaUtil 36%).
// Ledger: 8 loads/tile issued at p3/p4. At end-of-tile-u the per-wave window
// holds tile u+1's 8 + tile u+2's 8 -> vmcnt(8) retires exactly tile u+1.
// Tail: at u==KT-2 nothing was staged (only tile KT-1's 8 in window) ->
// vmcnt(0) (free; nothing left to prefetch). Prologue stages tiles 0,1 fully
// (16 loads), vmcnt(8) -> tile0 landed.
// =====================================================================
template<int KT>
__device__ __forceinline__ void gemm_core(
    const unsigned short* __restrict__ A,
    const unsigned short* __restrict__ B,
    const int K, const int m0, const int n0,
    unsigned short* sm, f32x4 (&acc)[8][4]) {
  const int tid  = threadIdx.x;
  const int w    = tid >> 6;
  const int lane = tid & 63;
  const int wr = w >> 2, wc = w & 3;   // 2 x 4 wave grid
  const int lr = lane & 15, lk = lane >> 4;

  // staging source pointers: wave w, q=0..3 -> chunk (w+8q): rowgroup 4q+(w>>1), kchunk w&1
  const unsigned short* gA[4];
  const unsigned short* gB[4];
#pragma unroll
  for (int q = 0; q < 4; ++q) {
    const int rg = 4 * q + (w >> 1);
    const size_t ro = (size_t)(rg * 16 + lr) * K + (w & 1) * 32 + lk * 8;
    gA[q] = A + (size_t)m0 * K + ro;
    gB[q] = B + (size_t)n0 * K + ro;
  }

  // ---- prologue: tile0 full (buf0) + tile1 full (buf1)
#pragma unroll
  for (int q = 0; q < 4; ++q) gld16(gA[q], sm + (w + 8 * q) * 512);
#pragma unroll
  for (int q = 0; q < 4; ++q) gld16(gB[q], sm + 32768 + (w + 8 * q) * 512);
#pragma unroll
  for (int q = 0; q < 4; ++q) gld16(gA[q] + 64, sm + 16384 + (w + 8 * q) * 512);
#pragma unroll
  for (int q = 0; q < 4; ++q) gld16(gB[q] + 64, sm + 32768 + 16384 + (w + 8 * q) * 512);
  asm volatile("s_waitcnt vmcnt(8)" ::: "memory");  // tile0 landed; tile1's 8 in flight
  __builtin_amdgcn_s_barrier();

  bf16x8 a[4][2], bb[4][2];

#pragma unroll 1
  for (int u = 0; u < KT; ++u) {
    const int bu = u & 1;
    unsigned short* cA = sm + bu * 16384;
    unsigned short* cB = sm + 32768 + bu * 16384;
    const int koff2 = (u + 2) * 64;

    // ---- phase 1: read A(qm0)+B(qn0); MFMA quad(0,0)
#pragma unroll
    for (int i = 0; i < 4; ++i)
#pragma unroll
      for (int kc = 0; kc < 2; ++kc)
        a[i][kc] = *(const bf16x8*)(cA + ((wr * 8 + i) * 2 + kc) * 512 + lane * 8);
#pragma unroll
    for (int j = 0; j < 2; ++j)
#pragma unroll
      for (int kc = 0; kc < 2; ++kc)
        bb[j][kc] = *(const bf16x8*)(cB + ((wc * 4 + j) * 2 + kc) * 512 + lane * 8);
    __builtin_amdgcn_s_barrier();
    asm volatile("s_waitcnt lgkmcnt(0)" ::: "memory");
    __builtin_amdgcn_sched_barrier(0);
    __builtin_amdgcn_s_setprio(1);
#pragma unroll
    for (int kc = 0; kc < 2; ++kc)
#pragma unroll
      for (int i = 0; i < 4; ++i)
#pragma unroll
        for (int j = 0; j < 2; ++j)
          acc[i][j] = mfma_bf16(a[i][kc], bb[j][kc], acc[i][j]);
    __builtin_amdgcn_s_setprio(0);
    __builtin_amdgcn_s_barrier();

    // ---- phase 2: read B(qn1); MFMA quad(0,1)
#pragma unroll
    for (int j = 0; j < 2; ++j)
#pragma unroll
      for (int kc = 0; kc < 2; ++kc)
        bb[2 + j][kc] = *(const bf16x8*)(cB + ((wc * 4 + 2 + j) * 2 + kc) * 512 + lane * 8);
    __builtin_amdgcn_s_barrier();
    asm volatile("s_waitcnt lgkmcnt(0)" ::: "memory");
    __builtin_amdgcn_sched_barrier(0);
    __builtin_amdgcn_s_setprio(1);
#pragma unroll
    for (int kc = 0; kc < 2; ++kc)
#pragma unroll
      for (int i = 0; i < 4; ++i)
#pragma unroll
        for (int j = 0; j < 2; ++j)
          acc[i][2 + j] = mfma_bf16(a[i][kc], bb[2 + j][kc], acc[i][2 + j]);
    __builtin_amdgcn_s_setprio(0);
    __builtin_amdgcn_s_barrier();

    // ---- phase 3: read A(qm1); stage ALL of B(u+2) into cB; MFMA quad(1,0)
    // (all B reads of tile u completed by p2's closing barrier)
#pragma unroll
    for (int i = 0; i < 4; ++i)
#pragma unroll
      for (int kc = 0; kc < 2; ++kc)
        a[i][kc] = *(const bf16x8*)(cA + ((wr * 8 + 4 + i) * 2 + kc) * 512 + lane * 8);
    if (u + 2 < KT) {
      gld16(gB[0] + koff2, cB + (w + 0) * 512);
      gld16(gB[1] + koff2, cB + (w + 8) * 512);
      gld16(gB[2] + koff2, cB + (w + 16) * 512);
      gld16(gB[3] + koff2, cB + (w + 24) * 512);
    }
    __builtin_amdgcn_s_barrier();
    asm volatile("s_waitcnt lgkmcnt(0)" ::: "memory");
    __builtin_amdgcn_sched_barrier(0);
    __builtin_amdgcn_s_setprio(1);
#pragma unroll
    for (int kc = 0; kc < 2; ++kc)
#pragma unroll
      for (int i = 0; i < 4; ++i)
#pragma unroll
        for (int j = 0; j < 2; ++j)
          acc[4 + i][j] = mfma_bf16(a[i][kc], bb[j][kc], acc[4 + i][j]);
    __builtin_amdgcn_s_setprio(0);
    __builtin_amdgcn_s_barrier();

    // ---- phase 4: stage ALL of A(u+2) into cA; MFMA quad(1,1); counted wait
    // (all A reads of tile u completed by p3's closing barrier)
    if (u + 2 < KT) {
      gld16(gA[0] + koff2, cA + (w + 0) * 512);
      gld16(gA[1] + koff2, cA + (w + 8) * 512);
      gld16(gA[2] + koff2, cA + (w + 16) * 512);
      gld16(gA[3] + koff2, cA + (w + 24) * 512);
    }
    __builtin_amdgcn_s_barrier();
    __builtin_amdgcn_s_setprio(1);
#pragma unroll
    for (int kc = 0; kc < 2; ++kc)
#pragma unroll
      for (int i = 0; i < 4; ++i)
#pragma unroll
        for (int j = 0; j < 2; ++j)
          acc[4 + i][2 + j] = mfma_bf16(a[i][kc], bb[2 + j][kc], acc[4 + i][2 + j]);
    __builtin_amdgcn_s_setprio(0);
    if (u == KT - 2) {
      // nothing staged this iteration: only tile KT-1's 8 loads in window;
      // vmcnt(8) would not wait for them. Full drain (free: nothing left to
      // prefetch).
      asm volatile("s_waitcnt vmcnt(0)" ::: "memory");
    } else {
      asm volatile("s_waitcnt vmcnt(8)" ::: "memory");  // tile u+1 fully landed
    }
    __builtin_amdgcn_s_barrier();
  }
}

// ---------------- GEMM1: x @ [w1|w3]' (16-col interleaved) + SwiGLU -> h ----------------
__global__ __launch_bounds__(512, 2) void gemm_gateup(
    const unsigned short* __restrict__ xb,
    const unsigned short* __restrict__ w13t,
    unsigned short* __restrict__ hbuf) {
  __shared__ __align__(16) unsigned short sm[65536];
  const int e = blockIdx.z;
  const int bid = blockIdx.x;                  // 512 blocks/expert
  const int sb = (bid & 7) * 64 + (bid >> 3);  // bijective XCD swizzle (512 % 8 == 0)
  const int mb = sb & 15, nb = sb >> 4;        // 16 x 32 tiles, mb fastest in chunk
  const int m0 = mb * 256, n0 = nb * 256;

  f32x4 acc[8][4] = {};
  gemm_core<D_ / 64>(xb + (size_t)e * TPE * D_,
                     w13t + (size_t)e * (2 * H_) * D_,
                     D_, m0, n0, sm, acc);

  // epilogue: n-frag pairs (even=gate, odd=up) share lane/column -> in-register SwiGLU
  const int tid = threadIdx.x;
  const int w = tid >> 6, lane = tid & 63;
  const int wr = w >> 2, wc = w & 3, lr = lane & 15, lk = lane >> 4;
  unsigned short* He = hbuf + (size_t)e * TPE * H_;
  const int rbase = m0 + wr * 128;
  const int cbase = n0 / 2 + wc * 32;
#pragma unroll
  for (int i = 0; i < 8; ++i)
#pragma unroll
    for (int jp = 0; jp < 2; ++jp)
#pragma unroll
      for (int r = 0; r < 4; ++r) {
        float g  = acc[i][2 * jp][r];
        float uu = acc[i][2 * jp + 1][r];
        float hv = (g / (1.0f + __expf(-g))) * uu;
        He[(size_t)(rbase + i * 16 + lk * 4 + r) * H_ + cbase + jp * 16 + lr] = f2bf(hv);
      }
}

// ---------------- GEMM2: out = h @ w2 (fp32 out) ----------------
__global__ __launch_bounds__(512, 2) void gemm_down(
    const unsigned short* __restrict__ hbuf,
    const unsigned short* __restrict__ w2t,
    float* __restrict__ out) {
  __shared__ __align__(16) unsigned short sm[65536];
  const int e = blockIdx.z;
  const int bid = blockIdx.x;                 // 64 blocks/expert
  const int sb = (bid & 7) * 8 + (bid >> 3);  // bijective XCD swizzle (64 % 8 == 0)
  const int mb = sb & 15, nb = sb >> 4;       // 16 x 4 tiles
  const int m0 = mb * 256, n0 = nb * 256;

  f32x4 acc[8][4] = {};
  gemm_core<H_ / 64>(hbuf + (size_t)e * TPE * H_,
                     w2t + (size_t)e * (size_t)D_ * H_,
                     H_, m0, n0, sm, acc);

  const int tid = threadIdx.x;
  const int w = tid >> 6, lane = tid & 63;
  const int wr = w >> 2, wc = w & 3, lr = lane & 15, lk = lane >> 4;
  float* Oe = out + (size_t)e * TPE * D_;
  const int rbase = m0 + wr * 128;
  const int cbase = n0 + wc * 64;
#pragma unroll
  for (int i = 0; i < 8; ++i)
#pragma unroll
    for (int j = 0; j < 4; ++j)
#pragma unroll
      for (int r = 0; r < 4; ++r)
        Oe[(size_t)(rbase + i * 16 + lk * 4 + r) * D_ + cbase + j * 16 + lr] = acc[i][j][r];
}

extern "C" void kernel_launch(void* const* d_in, const int* in_sizes, int n_in,
                              void* d_out, int out_size, void* d_ws, size_t ws_size,
                              hipStream_t stream) {
  const float* x  = (const float*)d_in[0];
  const float* w1 = (const float*)d_in[1];
  const float* w2 = (const float*)d_in[2];
  const float* w3 = (const float*)d_in[3];
  // d_in[4] = splits (uniform T/E, unused)

  char* ws = (char*)d_ws;
  unsigned short* xb   = (unsigned short*)(ws);                 //  64 MB  x  bf16
  unsigned short* w13t = (unsigned short*)(ws + (64ull << 20)); // 128 MB  [E][2H][D] interleaved
  unsigned short* w2t  = (unsigned short*)(ws + (192ull << 20)); //  64 MB  [E][D][H]
  unsigned short* hbuf = (unsigned short*)(ws + (256ull << 20)); // 256 MB  [E][TPE][H]
  float* out = (float*)d_out;

  // 1) convert / transpose to bf16 (w1/w3 interleaved into B')
  cvt_bf16<<<(T_ * D_) / 2048, 256, 0, stream>>>(x, xb);
  transpose_ilv_bf16<<<dim3(H_ / 64, D_ / 64, E_), 256, 0, stream>>>(w1, w13t, D_, H_, 0);
  transpose_ilv_bf16<<<dim3(H_ / 64, D_ / 64, E_), 256, 0, stream>>>(w3, w13t, D_, H_, 16);
  transpose_bf16<<<dim3(D_ / 64, H_ / 64, E_), 256, 0, stream>>>(w2, w2t, H_, D_);

  // 2) gate/up + SwiGLU -> h
  gemm_gateup<<<dim3(512, 1, E_), 512, 0, stream>>>(xb, w13t, hbuf);

  // 3) down projection -> out
  gemm_down<<<dim3(64, 1, E_), 512, 0, stream>>>(hbuf, w2t, out);
}

// Round 4
// 1423.878 us; speedup vs baseline: 1.0224x; 1.0224x over previous
//
#include <hip/hip_runtime.h>
#include <stdint.h>

#define E_  8
#define D_  1024
#define H_  4096
#define T_  32768
#define TPE 4096   // tokens per expert (uniform splits)

typedef __bf16 bf16x8 __attribute__((ext_vector_type(8)));
typedef float  f32x4  __attribute__((ext_vector_type(4)));
typedef float  f32x16 __attribute__((ext_vector_type(16)));
typedef unsigned short u16x4 __attribute__((ext_vector_type(4)));
typedef unsigned short u16x8 __attribute__((ext_vector_type(8)));

__device__ __forceinline__ unsigned short f2bf(float f) {
  union { float f; uint32_t u; } v; v.f = f;
  uint32_t u = v.u;
  return (unsigned short)((u + 0x7FFFu + ((u >> 16) & 1u)) >> 16);  // RNE
}

// async global->LDS, 16B per lane; LDS dest = wave-uniform base + lane*16
__device__ __forceinline__ void gld16(const unsigned short* g, unsigned short* l) {
  __builtin_amdgcn_global_load_lds(
      (const __attribute__((address_space(1))) unsigned int*)g,
      (__attribute__((address_space(3))) unsigned int*)l, 16, 0, 0);
}

__device__ __forceinline__ f32x16 mfma32(bf16x8 a, bf16x8 b, f32x16 c) {
  return __builtin_amdgcn_mfma_f32_32x32x16_bf16(a, b, c, 0, 0, 0);
}

// ---------------- fp32 -> bf16 straight convert (x) ----------------
__global__ void cvt_bf16(const float* __restrict__ in, unsigned short* __restrict__ out) {
  size_t i = ((size_t)blockIdx.x * 256 + threadIdx.x) * 8;
  float4 a = *(const float4*)(in + i);
  float4 b = *(const float4*)(in + i + 4);
  u16x8 o;
  o[0] = f2bf(a.x); o[1] = f2bf(a.y); o[2] = f2bf(a.z); o[3] = f2bf(a.w);
  o[4] = f2bf(b.x); o[5] = f2bf(b.y); o[6] = f2bf(b.z); o[7] = f2bf(b.w);
  *(u16x8*)(out + i) = o;
}

// ------------- fp32 [R][C] -> bf16 [C][R] per expert (plain, for w2) -------------
__global__ void transpose_bf16(const float* __restrict__ in, unsigned short* __restrict__ out,
                               int R, int C) {
  __shared__ unsigned short t[64][68];
  size_t eo = (size_t)blockIdx.z * R * C;
  const float* ine = in + eo;
  unsigned short* oute = out + eo;
  int r0 = blockIdx.y * 64, c0 = blockIdx.x * 64;
  int rl = threadIdx.x >> 4;
  int cl = (threadIdx.x & 15) * 4;
#pragma unroll
  for (int i = 0; i < 4; ++i) {
    int r = i * 16 + rl;
    float4 v = *(const float4*)(ine + (size_t)(r0 + r) * C + c0 + cl);
    t[cl + 0][r] = f2bf(v.x);
    t[cl + 1][r] = f2bf(v.y);
    t[cl + 2][r] = f2bf(v.z);
    t[cl + 3][r] = f2bf(v.w);
  }
  __syncthreads();
#pragma unroll
  for (int i = 0; i < 4; ++i) {
    int c = i * 16 + rl;
    *(u16x4*)(oute + (size_t)(c0 + c) * R + r0 + cl) = *(const u16x4*)&t[c][cl];
  }
}

// ---- fp32 [R][C] -> bf16 interleaved B' [2C][R]: source col cc -> out row
// 64*(cc>>5) + (cc&31) + off   (off=0: w1/gate 32-group, off=32: w3/up 32-group)
// 32-col granularity so one 32x32 MFMA n-block is all-gate or all-up ->
// gate=acc[mi][0], up=acc[mi][1] pair IN-LANE, same register.
__global__ void transpose_ilv_bf16(const float* __restrict__ in, unsigned short* __restrict__ out,
                                   int R, int C, int off) {
  __shared__ unsigned short t[64][68];
  const float* ine = in + (size_t)blockIdx.z * R * C;
  unsigned short* oute = out + (size_t)blockIdx.z * 2 * (size_t)R * C;
  int r0 = blockIdx.y * 64, c0 = blockIdx.x * 64;
  int rl = threadIdx.x >> 4;
  int cl = (threadIdx.x & 15) * 4;
#pragma unroll
  for (int i = 0; i < 4; ++i) {
    int r = i * 16 + rl;
    float4 v = *(const float4*)(ine + (size_t)(r0 + r) * C + c0 + cl);
    t[cl + 0][r] = f2bf(v.x);
    t[cl + 1][r] = f2bf(v.y);
    t[cl + 2][r] = f2bf(v.z);
    t[cl + 3][r] = f2bf(v.w);
  }
  __syncthreads();
#pragma unroll
  for (int i = 0; i < 4; ++i) {
    int c = i * 16 + rl;
    int rr = c0 + c;
    int orow = 64 * (rr >> 5) + (rr & 31) + off;
    *(u16x4*)(oute + (size_t)orow * R + r0 + cl) = *(const u16x4*)&t[c][cl];
  }
}

// =====================================================================
// 256x256 8-wave pipelined GEMM core — 32x32x16 MFMA variant.
// BK=64, double-buffered LDS (128KB), 4-phase K-step, counted vmcnt,
// raw s_barrier, setprio around MFMA. A [M][K], B [N][K], k-contiguous.
//
// LDS chunk = 32 rows x 16 k (1KB), fragment-ordered: lane l = kh*32+r holds
// row r, k-elems kh*8..kh*8+7 -> one ds_read_b128 = one 32x32x16 A/B operand,
// contiguous 1KB/wave, conflict-free. Tile = 32 chunks, idx c = rowblock*4 + kc.
// Wave w stages chunks w+8q (q=0..3), 2 per phase (ROUND-2 LEDGER, verified):
//   p1: A-half1(u+1)  p2: B-half1(u+1)  p3: B-half0(u+2)  p4: A-half0(u+2)
// Steady state: 12 loads in window at p4's wait; vmcnt(4) retires the 8 oldest
// = ALL of tile u+1. Tail: at u==KT-2 p3/p4 stage nothing (8 in window) ->
// vmcnt(0) there (free; nothing left to prefetch).
// Per phase: 8 MFMA (2 m-blocks x 1 n-block x 4 k-steps) -> half the
// instruction count of the 16x16x32 version at +15% pipe rate (m06 vs m119).
// =====================================================================
template<int KT>
__device__ __forceinline__ void gemm_core(
    const unsigned short* __restrict__ A,
    const unsigned short* __restrict__ B,
    const int K, const int m0, const int n0,
    unsigned short* sm, f32x16 (&acc)[4][2]) {
  const int tid  = threadIdx.x;
  const int w    = tid >> 6;
  const int lane = tid & 63;
  const int wr = w >> 2, wc = w & 3;   // 2 x 4 wave grid; wave output 128r x 64c
  const int lr = lane & 31;            // row/col within 32
  const int lh = lane >> 5;            // k-half

  // staging source pointers: wave w, q=0..3 -> chunk c=w+8q: rowblock c>>2, kchunk c&3
  const unsigned short* gA[4];
  const unsigned short* gB[4];
#pragma unroll
  for (int q = 0; q < 4; ++q) {
    const int c  = w + 8 * q;
    const int rb = c >> 2, kc = c & 3;
    const size_t ro = (size_t)(rb * 32 + lr) * K + kc * 16 + lh * 8;
    gA[q] = A + (size_t)m0 * K + ro;
    gB[q] = B + (size_t)n0 * K + ro;
  }

  // ---- prologue: tile0 full (buf0) + tile1 B-half0 + A-half0 (buf1)
#pragma unroll
  for (int q = 0; q < 4; ++q) gld16(gA[q], sm + (w + 8 * q) * 512);
#pragma unroll
  for (int q = 0; q < 4; ++q) gld16(gB[q], sm + 32768 + (w + 8 * q) * 512);
  gld16(gB[0] + 64, sm + 32768 + 16384 + (w + 0) * 512);
  gld16(gB[1] + 64, sm + 32768 + 16384 + (w + 8) * 512);
  gld16(gA[0] + 64, sm + 16384 + (w + 0) * 512);
  gld16(gA[1] + 64, sm + 16384 + (w + 8) * 512);
  asm volatile("s_waitcnt vmcnt(4)" ::: "memory");  // tile0 landed; tile1 partial in flight
  __builtin_amdgcn_s_barrier();

  bf16x8 a[2][4], bb[2][4];  // [m- or n-block][k-step]

#pragma unroll 1
  for (int u = 0; u < KT; ++u) {
    const int bu = u & 1;
    unsigned short* cA = sm + bu * 16384;
    unsigned short* cB = sm + 32768 + bu * 16384;
    unsigned short* nA = sm + (bu ^ 1) * 16384;
    unsigned short* nB = sm + 32768 + (bu ^ 1) * 16384;
    const int koff1 = (u + 1) * 64, koff2 = (u + 2) * 64;

    // ---- phase 1: read A(mi0,1)+B(nj0); stage A-half1(u+1); MFMA (mi0,1 x nj0)
#pragma unroll
    for (int i = 0; i < 2; ++i)
#pragma unroll
      for (int ks = 0; ks < 4; ++ks)
        a[i][ks] = *(const bf16x8*)(cA + ((wr * 4 + i) * 4 + ks) * 512 + lane * 8);
#pragma unroll
    for (int ks = 0; ks < 4; ++ks)
      bb[0][ks] = *(const bf16x8*)(cB + ((wc * 2 + 0) * 4 + ks) * 512 + lane * 8);
    if (u + 1 < KT) {
      gld16(gA[2] + koff1, nA + (w + 16) * 512);
      gld16(gA[3] + koff1, nA + (w + 24) * 512);
    }
    __builtin_amdgcn_s_barrier();
    asm volatile("s_waitcnt lgkmcnt(0)" ::: "memory");
    __builtin_amdgcn_sched_barrier(0);
    __builtin_amdgcn_s_setprio(1);
#pragma unroll
    for (int ks = 0; ks < 4; ++ks)
#pragma unroll
      for (int i = 0; i < 2; ++i)
        acc[i][0] = mfma32(a[i][ks], bb[0][ks], acc[i][0]);
    __builtin_amdgcn_s_setprio(0);
    __builtin_amdgcn_s_barrier();

    // ---- phase 2: read B(nj1); stage B-half1(u+1); MFMA (mi0,1 x nj1)
#pragma unroll
    for (int ks = 0; ks < 4; ++ks)
      bb[1][ks] = *(const bf16x8*)(cB + ((wc * 2 + 1) * 4 + ks) * 512 + lane * 8);
    if (u + 1 < KT) {
      gld16(gB[2] + koff1, nB + (w + 16) * 512);
      gld16(gB[3] + koff1, nB + (w + 24) * 512);
    }
    __builtin_amdgcn_s_barrier();
    asm volatile("s_waitcnt lgkmcnt(0)" ::: "memory");
    __builtin_amdgcn_sched_barrier(0);
    __builtin_amdgcn_s_setprio(1);
#pragma unroll
    for (int ks = 0; ks < 4; ++ks)
#pragma unroll
      for (int i = 0; i < 2; ++i)
        acc[i][1] = mfma32(a[i][ks], bb[1][ks], acc[i][1]);
    __builtin_amdgcn_s_setprio(0);
    __builtin_amdgcn_s_barrier();

    // ---- phase 3: read A(mi2,3); stage B-half0(u+2) into current buf; MFMA (mi2,3 x nj0)
#pragma unroll
    for (int i = 0; i < 2; ++i)
#pragma unroll
      for (int ks = 0; ks < 4; ++ks)
        a[i][ks] = *(const bf16x8*)(cA + ((wr * 4 + 2 + i) * 4 + ks) * 512 + lane * 8);
    if (u + 2 < KT) {
      gld16(gB[0] + koff2, cB + (w + 0) * 512);
      gld16(gB[1] + koff2, cB + (w + 8) * 512);
    }
    __builtin_amdgcn_s_barrier();
    asm volatile("s_waitcnt lgkmcnt(0)" ::: "memory");
    __builtin_amdgcn_sched_barrier(0);
    __builtin_amdgcn_s_setprio(1);
#pragma unroll
    for (int ks = 0; ks < 4; ++ks)
#pragma unroll
      for (int i = 0; i < 2; ++i)
        acc[2 + i][0] = mfma32(a[i][ks], bb[0][ks], acc[2 + i][0]);
    __builtin_amdgcn_s_setprio(0);
    __builtin_amdgcn_s_barrier();

    // ---- phase 4: stage A-half0(u+2) into current buf; MFMA (mi2,3 x nj1); counted wait
    if (u + 2 < KT) {
      gld16(gA[0] + koff2, cA + (w + 0) * 512);
      gld16(gA[1] + koff2, cA + (w + 8) * 512);
    }
    __builtin_amdgcn_s_barrier();
    __builtin_amdgcn_s_setprio(1);
#pragma unroll
    for (int ks = 0; ks < 4; ++ks)
#pragma unroll
      for (int i = 0; i < 2; ++i)
        acc[2 + i][1] = mfma32(a[i][ks], bb[1][ks], acc[2 + i][1]);
    __builtin_amdgcn_s_setprio(0);
    if (u == KT - 2) {
      // p3/p4 staged nothing: only tile KT-1's 8 loads in window; vmcnt(4)
      // would leave its half1 in flight. Full drain (free).
      asm volatile("s_waitcnt vmcnt(0)" ::: "memory");
    } else {
      asm volatile("s_waitcnt vmcnt(4)" ::: "memory");  // tile u+1 fully landed
    }
    __builtin_amdgcn_s_barrier();
  }
}

// ---------------- GEMM1: x @ [w1|w3]' (32-col interleaved) + SwiGLU -> h ----------------
__global__ __launch_bounds__(512, 2) void gemm_gateup(
    const unsigned short* __restrict__ xb,
    const unsigned short* __restrict__ w13t,
    unsigned short* __restrict__ hbuf) {
  __shared__ __align__(16) unsigned short sm[65536];
  const int e = blockIdx.z;
  const int bid = blockIdx.x;                  // 512 blocks/expert
  const int sb = (bid & 7) * 64 + (bid >> 3);  // bijective XCD swizzle (512 % 8 == 0)
  const int mb = sb & 15, nb = sb >> 4;        // 16 x 32 tiles, mb fastest in chunk
  const int m0 = mb * 256, n0 = nb * 256;

  f32x16 acc[4][2] = {};
  gemm_core<D_ / 64>(xb + (size_t)e * TPE * D_,
                     w13t + (size_t)e * (2 * H_) * D_,
                     D_, m0, n0, sm, acc);

  // epilogue: nj=0 block = gate, nj=1 = up for the SAME 32 h-cols -> in-lane SwiGLU.
  // 32x32 C/D layout: col=lane&31, row=(reg&3)+8*(reg>>2)+4*(lane>>5)
  const int tid = threadIdx.x;
  const int w = tid >> 6, lane = tid & 63;
  const int wr = w >> 2, wc = w & 3;
  unsigned short* He = hbuf + (size_t)e * TPE * H_;
  const int rbase = m0 + wr * 128 + 4 * (lane >> 5);
  const int hcol  = n0 / 2 + wc * 32 + (lane & 31);
#pragma unroll
  for (int mi = 0; mi < 4; ++mi)
#pragma unroll
    for (int r = 0; r < 16; ++r) {
      float g  = acc[mi][0][r];
      float uu = acc[mi][1][r];
      float hv = (g / (1.0f + __expf(-g))) * uu;
      int row = rbase + mi * 32 + (r & 3) + 8 * (r >> 2);
      He[(size_t)row * H_ + hcol] = f2bf(hv);
    }
}

// ---------------- GEMM2: out = h @ w2 (fp32 out) ----------------
__global__ __launch_bounds__(512, 2) void gemm_down(
    const unsigned short* __restrict__ hbuf,
    const unsigned short* __restrict__ w2t,
    float* __restrict__ out) {
  __shared__ __align__(16) unsigned short sm[65536];
  const int e = blockIdx.z;
  const int bid = blockIdx.x;                 // 64 blocks/expert
  const int sb = (bid & 7) * 8 + (bid >> 3);  // bijective XCD swizzle (64 % 8 == 0)
  const int mb = sb & 15, nb = sb >> 4;       // 16 x 4 tiles
  const int m0 = mb * 256, n0 = nb * 256;

  f32x16 acc[4][2] = {};
  gemm_core<H_ / 64>(hbuf + (size_t)e * TPE * H_,
                     w2t + (size_t)e * (size_t)D_ * H_,
                     H_, m0, n0, sm, acc);

  const int tid = threadIdx.x;
  const int w = tid >> 6, lane = tid & 63;
  const int wr = w >> 2, wc = w & 3;
  float* Oe = out + (size_t)e * TPE * D_;
  const int rbase = m0 + wr * 128 + 4 * (lane >> 5);
  const int cbase = n0 + wc * 64 + (lane & 31);
#pragma unroll
  for (int mi = 0; mi < 4; ++mi)
#pragma unroll
    for (int nj = 0; nj < 2; ++nj)
#pragma unroll
      for (int r = 0; r < 16; ++r) {
        int row = rbase + mi * 32 + (r & 3) + 8 * (r >> 2);
        Oe[(size_t)row * D_ + cbase + nj * 32] = acc[mi][nj][r];
      }
}

extern "C" void kernel_launch(void* const* d_in, const int* in_sizes, int n_in,
                              void* d_out, int out_size, void* d_ws, size_t ws_size,
                              hipStream_t stream) {
  const float* x  = (const float*)d_in[0];
  const float* w1 = (const float*)d_in[1];
  const float* w2 = (const float*)d_in[2];
  const float* w3 = (const float*)d_in[3];
  // d_in[4] = splits (uniform T/E, unused)

  char* ws = (char*)d_ws;
  unsigned short* xb   = (unsigned short*)(ws);                 //  64 MB  x  bf16
  unsigned short* w13t = (unsigned short*)(ws + (64ull << 20)); // 128 MB  [E][2H][D] interleaved
  unsigned short* w2t  = (unsigned short*)(ws + (192ull << 20)); //  64 MB  [E][D][H]
  unsigned short* hbuf = (unsigned short*)(ws + (256ull << 20)); // 256 MB  [E][TPE][H]
  float* out = (float*)d_out;

  // 1) convert / transpose to bf16 (w1/w3 interleaved into B', 32-col groups)
  cvt_bf16<<<(T_ * D_) / 2048, 256, 0, stream>>>(x, xb);
  transpose_ilv_bf16<<<dim3(H_ / 64, D_ / 64, E_), 256, 0, stream>>>(w1, w13t, D_, H_, 0);
  transpose_ilv_bf16<<<dim3(H_ / 64, D_ / 64, E_), 256, 0, stream>>>(w3, w13t, D_, H_, 32);
  transpose_bf16<<<dim3(D_ / 64, H_ / 64, E_), 256, 0, stream>>>(w2, w2t, H_, D_);

  // 2) gate/up + SwiGLU -> h
  gemm_gateup<<<dim3(512, 1, E_), 512, 0, stream>>>(xb, w13t, hbuf);

  // 3) down projection -> out
  gemm_down<<<dim3(64, 1, E_), 512, 0, stream>>>(hbuf, w2t, out);
}

// Round 5
// 1332.802 us; speedup vs baseline: 1.0923x; 1.0683x over previous
//
#include <hip/hip_runtime.h>
#include <stdint.h>

#define E_  8
#define D_  1024
#define H_  4096
#define T_  32768
#define TPE 4096   // tokens per expert (uniform splits)

typedef __bf16 bf16x8 __attribute__((ext_vector_type(8)));
typedef float  f32x4  __attribute__((ext_vector_type(4)));
typedef unsigned short u16x4 __attribute__((ext_vector_type(4)));
typedef unsigned short u16x8 __attribute__((ext_vector_type(8)));

__device__ __forceinline__ unsigned short f2bf(float f) {
  union { float f; uint32_t u; } v; v.f = f;
  uint32_t u = v.u;
  return (unsigned short)((u + 0x7FFFu + ((u >> 16) & 1u)) >> 16);  // RNE
}

// async global->LDS, 16B per lane; LDS dest = wave-uniform base + lane*16
__device__ __forceinline__ void gld16(const unsigned short* g, unsigned short* l) {
  __builtin_amdgcn_global_load_lds(
      (const __attribute__((address_space(1))) unsigned int*)g,
      (__attribute__((address_space(3))) unsigned int*)l, 16, 0, 0);
}

__device__ __forceinline__ f32x4 mfma_bf16(bf16x8 a, bf16x8 b, f32x4 c) {
  return __builtin_amdgcn_mfma_f32_16x16x32_bf16(a, b, c, 0, 0, 0);
}

// ---------------- fp32 -> bf16 straight convert (x) ----------------
__global__ void cvt_bf16(const float* __restrict__ in, unsigned short* __restrict__ out) {
  size_t i = ((size_t)blockIdx.x * 256 + threadIdx.x) * 8;
  float4 a = *(const float4*)(in + i);
  float4 b = *(const float4*)(in + i + 4);
  u16x8 o;
  o[0] = f2bf(a.x); o[1] = f2bf(a.y); o[2] = f2bf(a.z); o[3] = f2bf(a.w);
  o[4] = f2bf(b.x); o[5] = f2bf(b.y); o[6] = f2bf(b.z); o[7] = f2bf(b.w);
  *(u16x8*)(out + i) = o;
}

// ------------- fp32 [R][C] -> bf16 [C][R] per expert (plain, for w2) -------------
__global__ void transpose_bf16(const float* __restrict__ in, unsigned short* __restrict__ out,
                               int R, int C) {
  __shared__ unsigned short t[64][68];
  size_t eo = (size_t)blockIdx.z * R * C;
  const float* ine = in + eo;
  unsigned short* oute = out + eo;
  int r0 = blockIdx.y * 64, c0 = blockIdx.x * 64;
  int rl = threadIdx.x >> 4;
  int cl = (threadIdx.x & 15) * 4;
#pragma unroll
  for (int i = 0; i < 4; ++i) {
    int r = i * 16 + rl;
    float4 v = *(const float4*)(ine + (size_t)(r0 + r) * C + c0 + cl);
    t[cl + 0][r] = f2bf(v.x);
    t[cl + 1][r] = f2bf(v.y);
    t[cl + 2][r] = f2bf(v.z);
    t[cl + 3][r] = f2bf(v.w);
  }
  __syncthreads();
#pragma unroll
  for (int i = 0; i < 4; ++i) {
    int c = i * 16 + rl;
    *(u16x4*)(oute + (size_t)(c0 + c) * R + r0 + cl) = *(const u16x4*)&t[c][cl];
  }
}

// ---- fp32 [R][C] -> bf16 interleaved B' [2C][R]: source col cc -> out row
// 32*(cc>>4) + (cc&15) + off   (off=0: w1/gate 16-group, off=16: w3/up 16-group)
__global__ void transpose_ilv_bf16(const float* __restrict__ in, unsigned short* __restrict__ out,
                                   int R, int C, int off) {
  __shared__ unsigned short t[64][68];
  const float* ine = in + (size_t)blockIdx.z * R * C;
  unsigned short* oute = out + (size_t)blockIdx.z * 2 * (size_t)R * C;
  int r0 = blockIdx.y * 64, c0 = blockIdx.x * 64;
  int rl = threadIdx.x >> 4;
  int cl = (threadIdx.x & 15) * 4;
#pragma unroll
  for (int i = 0; i < 4; ++i) {
    int r = i * 16 + rl;
    float4 v = *(const float4*)(ine + (size_t)(r0 + r) * C + c0 + cl);
    t[cl + 0][r] = f2bf(v.x);
    t[cl + 1][r] = f2bf(v.y);
    t[cl + 2][r] = f2bf(v.z);
    t[cl + 3][r] = f2bf(v.w);
  }
  __syncthreads();
#pragma unroll
  for (int i = 0; i < 4; ++i) {
    int c = i * 16 + rl;
    int rr = c0 + c;
    int orow = 32 * (rr >> 4) + (rr & 15) + off;
    *(u16x4*)(oute + (size_t)orow * R + r0 + cl) = *(const u16x4*)&t[c][cl];
  }
}

// =====================================================================
// PERSISTENT 256x256 8-wave pipelined GEMM core (round-2 verified ledger,
// 16x16x32 MFMA). One block owns NT m-tiles of ONE n-panel; the K-loop is a
// single global step loop v in [0, NT*KT) running the verified 4-phase
// schedule SEAMLESSLY across tile boundaries (KT even -> LDS parity
// continuous). Staging (per wave, 2 gld16/phase):
//   p1: A-half1(v+1)  p2: B-half1(v+1)  p3: B-half0(v+2)  p4: A-half0(v+2)
// Ledger at p4's wait: 12 staging loads in window; the 4 newest (p3/p4 of v,
// step v+2 half0s) may remain -> vmcnt(4) retires ALL of step v+1. Epilogue
// stores (once per KT steps) entering the window only make the wait
// conservative (stores are newer than the protected loads). Tail: at v==V-2
// p3/p4 stage nothing -> vmcnt(0) (free; nothing left to prefetch).
// Tile-end epilogue runs after p4's closing barrier: touches only acc +
// global stores (no LDS) -> region-safe against next phase's ds_reads.
// A = block's m-panel base [NT*256][K]; B = block's n-panel base [256][K].
// =====================================================================
template<int KT, int NT, typename EPI>
__device__ __forceinline__ void gemm_persist(
    const unsigned short* __restrict__ A,
    const unsigned short* __restrict__ B,
    const int K, unsigned short* sm, f32x4 (&acc)[8][4], EPI epi) {
  constexpr int V = KT * NT;
  constexpr int LOGKT = (KT == 16) ? 4 : 6;  // KT in {16, 64}
  static_assert(KT == (1 << LOGKT), "KT must be 16 or 64");
  const int tid  = threadIdx.x;
  const int w    = tid >> 6;
  const int lane = tid & 63;
  const int wr = w >> 2, wc = w & 3;   // 2 x 4 wave grid
  const int lr = lane & 15, lk = lane >> 4;

  // per-step global offsets: m-tile advances every KT steps (A only)
  auto aoff = [&](int vv) -> size_t {
    return (size_t)((vv >> LOGKT) * 256) * (size_t)K + (size_t)((vv & (KT - 1)) * 64);
  };
  auto boff = [&](int vv) -> size_t {
    return (size_t)((vv & (KT - 1)) * 64);
  };

  // staging source pointers (tile-relative): wave w, q=0..3 -> chunk w+8q
  const unsigned short* gA[4];
  const unsigned short* gB[4];
#pragma unroll
  for (int q = 0; q < 4; ++q) {
    const int rg = 4 * q + (w >> 1);
    const size_t ro = (size_t)(rg * 16 + lr) * K + (w & 1) * 32 + lk * 8;
    gA[q] = A + ro;
    gB[q] = B + ro;
  }

  // ---- prologue: step0 full (buf0) + step1 B-half0 + A-half0 (buf1)
  {
    const size_t a1 = aoff(1), b1 = boff(1);
#pragma unroll
    for (int q = 0; q < 4; ++q) gld16(gA[q], sm + (w + 8 * q) * 512);
#pragma unroll
    for (int q = 0; q < 4; ++q) gld16(gB[q], sm + 32768 + (w + 8 * q) * 512);
    gld16(gB[0] + b1, sm + 32768 + 16384 + (w + 0) * 512);
    gld16(gB[1] + b1, sm + 32768 + 16384 + (w + 8) * 512);
    gld16(gA[0] + a1, sm + 16384 + (w + 0) * 512);
    gld16(gA[1] + a1, sm + 16384 + (w + 8) * 512);
  }
  asm volatile("s_waitcnt vmcnt(4)" ::: "memory");  // step0 landed; step1 partial in flight
  __builtin_amdgcn_s_barrier();

  bf16x8 a[4][2], bb[4][2];

#pragma unroll 1
  for (int v = 0; v < V; ++v) {
    const int bu = v & 1;
    unsigned short* cA = sm + bu * 16384;
    unsigned short* cB = sm + 32768 + bu * 16384;
    unsigned short* nA = sm + (bu ^ 1) * 16384;
    unsigned short* nB = sm + 32768 + (bu ^ 1) * 16384;
    const int v1 = v + 1, v2 = v + 2;

    // ---- phase 1: read A(qm0)+B(qn0); stage A-half1(v+1); MFMA quad(0,0)
#pragma unroll
    for (int i = 0; i < 4; ++i)
#pragma unroll
      for (int kc = 0; kc < 2; ++kc)
        a[i][kc] = *(const bf16x8*)(cA + ((wr * 8 + i) * 2 + kc) * 512 + lane * 8);
#pragma unroll
    for (int j = 0; j < 2; ++j)
#pragma unroll
      for (int kc = 0; kc < 2; ++kc)
        bb[j][kc] = *(const bf16x8*)(cB + ((wc * 4 + j) * 2 + kc) * 512 + lane * 8);
    if (v1 < V) {
      const size_t ao = aoff(v1);
      gld16(gA[2] + ao, nA + (w + 16) * 512);
      gld16(gA[3] + ao, nA + (w + 24) * 512);
    }
    __builtin_amdgcn_s_barrier();
    asm volatile("s_waitcnt lgkmcnt(0)" ::: "memory");
    __builtin_amdgcn_sched_barrier(0);
    __builtin_amdgcn_s_setprio(1);
#pragma unroll
    for (int i = 0; i < 4; ++i)
#pragma unroll
      for (int j = 0; j < 2; ++j)
#pragma unroll
        for (int kc = 0; kc < 2; ++kc)
          acc[i][j] = mfma_bf16(a[i][kc], bb[j][kc], acc[i][j]);
    __builtin_amdgcn_s_setprio(0);
    __builtin_amdgcn_s_barrier();

    // ---- phase 2: read B(qn1); stage B-half1(v+1); MFMA quad(0,1)
#pragma unroll
    for (int j = 0; j < 2; ++j)
#pragma unroll
      for (int kc = 0; kc < 2; ++kc)
        bb[2 + j][kc] = *(const bf16x8*)(cB + ((wc * 4 + 2 + j) * 2 + kc) * 512 + lane * 8);
    if (v1 < V) {
      const size_t bo = boff(v1);
      gld16(gB[2] + bo, nB + (w + 16) * 512);
      gld16(gB[3] + bo, nB + (w + 24) * 512);
    }
    __builtin_amdgcn_s_barrier();
    asm volatile("s_waitcnt lgkmcnt(0)" ::: "memory");
    __builtin_amdgcn_sched_barrier(0);
    __builtin_amdgcn_s_setprio(1);
#pragma unroll
    for (int i = 0; i < 4; ++i)
#pragma unroll
      for (int j = 0; j < 2; ++j)
#pragma unroll
        for (int kc = 0; kc < 2; ++kc)
          acc[i][2 + j] = mfma_bf16(a[i][kc], bb[2 + j][kc], acc[i][2 + j]);
    __builtin_amdgcn_s_setprio(0);
    __builtin_amdgcn_s_barrier();

    // ---- phase 3: read A(qm1); stage B-half0(v+2) into current buf; MFMA quad(1,0)
#pragma unroll
    for (int i = 0; i < 4; ++i)
#pragma unroll
      for (int kc = 0; kc < 2; ++kc)
        a[i][kc] = *(const bf16x8*)(cA + ((wr * 8 + 4 + i) * 2 + kc) * 512 + lane * 8);
    if (v2 < V) {
      const size_t bo = boff(v2);
      gld16(gB[0] + bo, cB + (w + 0) * 512);
      gld16(gB[1] + bo, cB + (w + 8) * 512);
    }
    __builtin_amdgcn_s_barrier();
    asm volatile("s_waitcnt lgkmcnt(0)" ::: "memory");
    __builtin_amdgcn_sched_barrier(0);
    __builtin_amdgcn_s_setprio(1);
#pragma unroll
    for (int i = 0; i < 4; ++i)
#pragma unroll
      for (int j = 0; j < 2; ++j)
#pragma unroll
        for (int kc = 0; kc < 2; ++kc)
          acc[4 + i][j] = mfma_bf16(a[i][kc], bb[j][kc], acc[4 + i][j]);
    __builtin_amdgcn_s_setprio(0);
    __builtin_amdgcn_s_barrier();

    // ---- phase 4: stage A-half0(v+2) into current buf; MFMA quad(1,1); counted wait
    if (v2 < V) {
      const size_t ao = aoff(v2);
      gld16(gA[0] + ao, cA + (w + 0) * 512);
      gld16(gA[1] + ao, cA + (w + 8) * 512);
    }
    __builtin_amdgcn_s_barrier();
    __builtin_amdgcn_s_setprio(1);
#pragma unroll
    for (int i = 0; i < 4; ++i)
#pragma unroll
      for (int j = 0; j < 2; ++j)
#pragma unroll
        for (int kc = 0; kc < 2; ++kc)
          acc[4 + i][2 + j] = mfma_bf16(a[i][kc], bb[2 + j][kc], acc[4 + i][2 + j]);
    __builtin_amdgcn_s_setprio(0);
    if (v == V - 2) {
      asm volatile("s_waitcnt vmcnt(0)" ::: "memory");
    } else {
      asm volatile("s_waitcnt vmcnt(4)" ::: "memory");  // step v+1 fully landed
    }
    __builtin_amdgcn_s_barrier();

    // ---- tile boundary: epilogue for finished tile, reset accumulator
    if ((v & (KT - 1)) == (KT - 1)) {
      epi(v >> LOGKT);
#pragma unroll
      for (int i = 0; i < 8; ++i)
#pragma unroll
        for (int j = 0; j < 4; ++j)
          acc[i][j] = f32x4{0.f, 0.f, 0.f, 0.f};
    }
  }
}

// ---------------- GEMM1: x @ [w1|w3]' (16-col interleaved) + SwiGLU -> h ----------------
// Persistent: 32 blocks/expert, each owns one 256-wide B' n-panel (L2-resident
// across the block) and loops all 16 m-tiles.
__global__ __launch_bounds__(512, 2) void gemm_gateup(
    const unsigned short* __restrict__ xb,
    const unsigned short* __restrict__ w13t,
    unsigned short* __restrict__ hbuf) {
  __shared__ __align__(16) unsigned short sm[65536];
  const int e  = blockIdx.z;
  const int nb = blockIdx.x;        // 0..31: n-panel index
  const int n0 = nb * 256;

  const unsigned short* A = xb + (size_t)e * TPE * D_;
  const unsigned short* B = w13t + (size_t)e * (2 * H_) * D_ + (size_t)n0 * D_;
  unsigned short* He = hbuf + (size_t)e * TPE * H_;

  const int tid = threadIdx.x;
  const int w = tid >> 6, lane = tid & 63;
  const int wr = w >> 2, wc = w & 3, lr = lane & 15, lk = lane >> 4;

  f32x4 acc[8][4] = {};
  auto epi = [&](int t) {
    const int rbase = t * 256 + wr * 128;
    const int cbase = n0 / 2 + wc * 32;
#pragma unroll
    for (int i = 0; i < 8; ++i)
#pragma unroll
      for (int jp = 0; jp < 2; ++jp)
#pragma unroll
        for (int r = 0; r < 4; ++r) {
          float g  = acc[i][2 * jp][r];
          float uu = acc[i][2 * jp + 1][r];
          float hv = (g / (1.0f + __expf(-g))) * uu;
          He[(size_t)(rbase + i * 16 + lk * 4 + r) * H_ + cbase + jp * 16 + lr] = f2bf(hv);
        }
  };
  gemm_persist<16, 16>(A, B, D_, sm, acc, epi);
}

// ---------------- GEMM2: out = h @ w2 (fp32 out) ----------------
// Persistent: 32 blocks/expert: n-panel = x&3, m-pair = x>>2 (2 tiles each).
__global__ __launch_bounds__(512, 2) void gemm_down(
    const unsigned short* __restrict__ hbuf,
    const unsigned short* __restrict__ w2t,
    float* __restrict__ out) {
  __shared__ __align__(16) unsigned short sm[65536];
  const int e  = blockIdx.z;
  const int x  = blockIdx.x;        // 0..31
  const int nb = x & 3, mp = x >> 2;
  const int n0 = nb * 256;
  const int mbase = mp * 512;

  const unsigned short* A = hbuf + (size_t)e * TPE * H_ + (size_t)mbase * H_;
  const unsigned short* B = w2t + (size_t)e * (size_t)D_ * H_ + (size_t)n0 * H_;
  float* Oe = out + (size_t)e * TPE * D_;

  const int tid = threadIdx.x;
  const int w = tid >> 6, lane = tid & 63;
  const int wr = w >> 2, wc = w & 3, lr = lane & 15, lk = lane >> 4;

  f32x4 acc[8][4] = {};
  auto epi = [&](int t) {
    const int rbase = mbase + t * 256 + wr * 128;
    const int cbase = n0 + wc * 64;
#pragma unroll
    for (int i = 0; i < 8; ++i)
#pragma unroll
      for (int j = 0; j < 4; ++j)
#pragma unroll
        for (int r = 0; r < 4; ++r)
          Oe[(size_t)(rbase + i * 16 + lk * 4 + r) * D_ + cbase + j * 16 + lr] = acc[i][j][r];
  };
  gemm_persist<64, 2>(A, B, H_, sm, acc, epi);
}

extern "C" void kernel_launch(void* const* d_in, const int* in_sizes, int n_in,
                              void* d_out, int out_size, void* d_ws, size_t ws_size,
                              hipStream_t stream) {
  const float* x  = (const float*)d_in[0];
  const float* w1 = (const float*)d_in[1];
  const float* w2 = (const float*)d_in[2];
  const float* w3 = (const float*)d_in[3];
  // d_in[4] = splits (uniform T/E, unused)

  char* ws = (char*)d_ws;
  unsigned short* xb   = (unsigned short*)(ws);                 //  64 MB  x  bf16
  unsigned short* w13t = (unsigned short*)(ws + (64ull << 20)); // 128 MB  [E][2H][D] interleaved
  unsigned short* w2t  = (unsigned short*)(ws + (192ull << 20)); //  64 MB  [E][D][H]
  unsigned short* hbuf = (unsigned short*)(ws + (256ull << 20)); // 256 MB  [E][TPE][H]
  float* out = (float*)d_out;

  // 1) convert / transpose to bf16 (w1/w3 interleaved into B', 16-col groups)
  cvt_bf16<<<(T_ * D_) / 2048, 256, 0, stream>>>(x, xb);
  transpose_ilv_bf16<<<dim3(H_ / 64, D_ / 64, E_), 256, 0, stream>>>(w1, w13t, D_, H_, 0);
  transpose_ilv_bf16<<<dim3(H_ / 64, D_ / 64, E_), 256, 0, stream>>>(w3, w13t, D_, H_, 16);
  transpose_bf16<<<dim3(D_ / 64, H_ / 64, E_), 256, 0, stream>>>(w2, w2t, H_, D_);

  // 2) gate/up + SwiGLU -> h   (persistent: 256 blocks = 1/CU)
  gemm_gateup<<<dim3(32, 1, E_), 512, 0, stream>>>(xb, w13t, hbuf);

  // 3) down projection -> out  (persistent: 256 blocks = 1/CU)
  gemm_down<<<dim3(32, 1, E_), 512, 0, stream>>>(hbuf, w2t, out);
}